// Round 1
// baseline (1278.648 us; speedup 1.0000x reference)
//
#include <hip/hip_runtime.h>

#define T_STEPS 20
#define KK      20
#define NW      50000
#define DD      64

typedef __attribute__((ext_vector_type(8))) short bfx8;
typedef __attribute__((ext_vector_type(4))) short sx4;
typedef __attribute__((ext_vector_type(4))) float fx4;

__device__ __forceinline__ short f2bf(float f){
  unsigned u = __builtin_bit_cast(unsigned, f);
  return (short)((u + 0x7FFFu + ((u >> 16) & 1u)) >> 16);
}
__device__ __forceinline__ float hsig(float x){ return fminf(fmaxf(fmaf(x, 0.16666667f, 0.5f), 0.f), 1.f); }
__device__ __forceinline__ float htanh(float x){ return fminf(fmaxf(x, -1.f), 1.f); }

// Build an 8-elem bf16 fragment from two 4-float chunks (k-map: elems 0..3 <- p0, 4..7 <- p1).
// The same (group,elem)->k convention is used for EVERY A and B fragment, so the exact HW
// k-map cancels (consistent permutation of the contraction index).
__device__ __forceinline__ bfx8 frag_f32(const float* p0, const float* p1){
  fx4 lo = *(const fx4*)p0, hi = *(const fx4*)p1;
  bfx8 r;
  r[0]=f2bf(lo[0]); r[1]=f2bf(lo[1]); r[2]=f2bf(lo[2]); r[3]=f2bf(lo[3]);
  r[4]=f2bf(hi[0]); r[5]=f2bf(hi[1]); r[6]=f2bf(hi[2]); r[7]=f2bf(hi[3]);
  return r;
}
__device__ __forceinline__ bfx8 frag_lds(const unsigned short* p0, const unsigned short* p1){
  sx4 lo = *(const sx4*)p0, hi = *(const sx4*)p1;
  bfx8 r;
  r[0]=lo[0]; r[1]=lo[1]; r[2]=lo[2]; r[3]=lo[3];
  r[4]=hi[0]; r[5]=hi[1]; r[6]=hi[2]; r[7]=hi[3];
  return r;
}

// Block = 16 cells: k = k0 + (row&3), n = n0 + (row>>2), row = 0..15.
// Wave w owns hidden-dim slice d in [w*16, w*16+16); gate cols j = type*64 + w*16 + (lane&15).
// C layout (HW-verified): col = lane&15, row = (lane>>4)*4 + reg.
__global__ __launch_bounds__(256)
void gcrl_fused(const float* __restrict__ obs, const float* __restrict__ pred,
                const float* __restrict__ w1, const float* __restrict__ b1,
                const float* __restrict__ w2, const float* __restrict__ b2,
                const float* __restrict__ wih, const float* __restrict__ whh,
                const float* __restrict__ bih, const float* __restrict__ bhh,
                const float* __restrict__ posw, const float* __restrict__ posb,
                float* __restrict__ out)
{
  __shared__ unsigned short hbuf[2][16][72];   // h state, bf16, 144B row stride (2-way banks)
  __shared__ unsigned short l1buf[16][36];     // MLP mid layer
  __shared__ float xs[19][4][2];               // obs rows 0..18 for this block's 4 n's

  const int tid = threadIdx.x;
  const int w   = tid >> 6;        // wave 0..3
  const int l   = tid & 63;
  const int g   = l >> 4;          // lane group 0..3
  const int cc  = l & 15;

  const int bid = blockIdx.x;
  const int k0  = (bid % 5) * 4;
  const int n0  = (bid / 5) * 4;

  // ---- stage x (obs) into LDS: rows 0..18, 4 n's, 2 comps ----
  for (int i = tid; i < 19 * 8; i += 256){
    int row = i >> 3, r = i & 7;
    xs[row][r >> 1][r & 1] = obs[(size_t)row * (NW * 2) + (size_t)(n0 + (r >> 1)) * 2 + (r & 1)];
  }

  // ---- recurrent weight fragments (registers, bf16) + x-path scalars ----
  bfx8 wf[4][2];
  float wx0[4], wx1[4], bsum[4];
  #pragma unroll
  for (int ty = 0; ty < 4; ++ty){
    const int j = ty * 64 + w * 16 + cc;               // gate row of w_hh / w_ih
    wx0[ty]  = wih[j * 2 + 0];
    wx1[ty]  = wih[j * 2 + 1];
    bsum[ty] = bih[j] + bhh[j];
    #pragma unroll
    for (int kt = 0; kt < 2; ++kt)
      wf[ty][kt] = frag_f32(&whh[j * DD + kt * 32 + g * 4],
                            &whh[j * DD + kt * 32 + 16 + g * 4]);
  }

  // ---- output-projection fragments (cols >=2 are garbage but never stored) ----
  const int c2 = (cc < 2) ? cc : 0;
  bfx8 pf[2];
  #pragma unroll
  for (int kt = 0; kt < 2; ++kt)
    pf[kt] = frag_f32(&posw[c2 * DD + kt * 32 + g * 4],
                      &posw[c2 * DD + kt * 32 + 16 + g * 4]);
  const float pbias = posb[c2];

  // ---- h0 MLP: leaky(P@W1^T+b1)@W2^T+b2 via MFMA ----
  {
    const int kcell = k0 + (cc & 3);
    const int ncell = n0 + (cc >> 2);
    const float* Pr = pred + ((size_t)kcell * NW + ncell) * DD;
    bfx8 pa0 = frag_f32(&Pr[g * 4],      &Pr[16 + g * 4]);
    bfx8 pa1 = frag_f32(&Pr[32 + g * 4], &Pr[48 + g * 4]);
    if (w == 0){
      #pragma unroll
      for (int nt = 0; nt < 2; ++nt){
        const int j1 = nt * 16 + cc;                   // 0..31
        bfx8 bf0 = frag_f32(&w1[j1 * DD + g * 4],      &w1[j1 * DD + 16 + g * 4]);
        bfx8 bf1 = frag_f32(&w1[j1 * DD + 32 + g * 4], &w1[j1 * DD + 48 + g * 4]);
        const float bb = b1[j1];
        fx4 acc = {bb, bb, bb, bb};
        acc = __builtin_amdgcn_mfma_f32_16x16x32_bf16(pa0, bf0, acc, 0, 0, 0);
        acc = __builtin_amdgcn_mfma_f32_16x16x32_bf16(pa1, bf1, acc, 0, 0, 0);
        #pragma unroll
        for (int r = 0; r < 4; ++r){
          float xv = acc[r];
          l1buf[g * 4 + r][nt * 16 + cc] =
            (unsigned short)f2bf(fmaxf(xv, 0.f) + 0.01f * fminf(xv, 0.f));
        }
      }
    }
  }
  __syncthreads();
  {
    bfx8 a2 = frag_lds(&l1buf[cc][g * 4], &l1buf[cc][16 + g * 4]);
    const int j2 = w * 16 + cc;                        // this wave's d-slice
    bfx8 b2f = frag_f32(&w2[j2 * 32 + g * 4], &w2[j2 * 32 + 16 + g * 4]);
    const float bb = b2[j2];
    fx4 acc = {bb, bb, bb, bb};
    acc = __builtin_amdgcn_mfma_f32_16x16x32_bf16(a2, b2f, acc, 0, 0, 0);
    #pragma unroll
    for (int r = 0; r < 4; ++r)
      hbuf[0][g * 4 + r][w * 16 + cc] = (unsigned short)f2bf(acc[r]);
  }
  float cst[4] = {0.f, 0.f, 0.f, 0.f};
  __syncthreads();

  // ---- 20-step LSTM scan; h stays in LDS (bf16), c stays in registers (f32) ----
  #pragma unroll 2
  for (int t = 0; t < T_STEPS; ++t){
    const int xi = (t == 0) ? 0 : (t - 1);             // idx = [0,0,1,...,18]
    const float x0v = xs[xi][g][0];
    const float x1v = xs[xi][g][1];

    const unsigned short* hrow = &hbuf[t & 1][cc][0];
    bfx8 ha0 = frag_lds(&hrow[g * 4],      &hrow[16 + g * 4]);
    bfx8 ha1 = frag_lds(&hrow[32 + g * 4], &hrow[48 + g * 4]);

    fx4 acc[4];
    #pragma unroll
    for (int ty = 0; ty < 4; ++ty){
      const float xv = fmaf(wx0[ty], x0v, fmaf(wx1[ty], x1v, bsum[ty]));
      fx4 a = {xv, xv, xv, xv};                        // x-part + biases as C-input
      a = __builtin_amdgcn_mfma_f32_16x16x32_bf16(ha0, wf[ty][0], a, 0, 0, 0);
      a = __builtin_amdgcn_mfma_f32_16x16x32_bf16(ha1, wf[ty][1], a, 0, 0, 0);
      acc[ty] = a;
    }

    // output projection of h_t (state entering this step) -> out[t-1]; wave 0 only
    if (w == 0 && t > 0){
      fx4 oa = {pbias, pbias, pbias, pbias};
      oa = __builtin_amdgcn_mfma_f32_16x16x32_bf16(ha0, pf[0], oa, 0, 0, 0);
      oa = __builtin_amdgcn_mfma_f32_16x16x32_bf16(ha1, pf[1], oa, 0, 0, 0);
      if (cc < 2){
        #pragma unroll
        for (int r = 0; r < 4; ++r)
          out[(((size_t)(t - 1) * KK + (k0 + r)) * NW + (n0 + g)) * 2 + cc] = oa[r];
      }
    }

    #pragma unroll
    for (int r = 0; r < 4; ++r){
      const float iv = acc[0][r], fv = acc[1][r], gv = acc[2][r], ov = acc[3][r];
      const float cn = fmaf(hsig(fv), cst[r], hsig(iv) * htanh(gv));
      cst[r] = cn;
      hbuf[(t + 1) & 1][g * 4 + r][w * 16 + cc] = (unsigned short)f2bf(hsig(ov) * htanh(cn));
    }
    __syncthreads();
  }

  // ---- epilogue: out[19] from final state (in hbuf[0]) ----
  if (w == 0){
    const unsigned short* hrow = &hbuf[0][cc][0];
    bfx8 ha0 = frag_lds(&hrow[g * 4],      &hrow[16 + g * 4]);
    bfx8 ha1 = frag_lds(&hrow[32 + g * 4], &hrow[48 + g * 4]);
    fx4 oa = {pbias, pbias, pbias, pbias};
    oa = __builtin_amdgcn_mfma_f32_16x16x32_bf16(ha0, pf[0], oa, 0, 0, 0);
    oa = __builtin_amdgcn_mfma_f32_16x16x32_bf16(ha1, pf[1], oa, 0, 0, 0);
    if (cc < 2){
      #pragma unroll
      for (int r = 0; r < 4; ++r)
        out[(((size_t)19 * KK + (k0 + r)) * NW + (n0 + g)) * 2 + cc] = oa[r];
    }
  }
}

extern "C" void kernel_launch(void* const* d_in, const int* in_sizes, int n_in,
                              void* d_out, int out_size, void* d_ws, size_t ws_size,
                              hipStream_t stream){
  const float* obs  = (const float*)d_in[0];
  const float* pred = (const float*)d_in[1];
  const float* w1   = (const float*)d_in[2];
  const float* b1   = (const float*)d_in[3];
  const float* w2   = (const float*)d_in[4];
  const float* b2   = (const float*)d_in[5];
  const float* wih  = (const float*)d_in[6];
  const float* whh  = (const float*)d_in[7];
  const float* bih  = (const float*)d_in[8];
  const float* bhh  = (const float*)d_in[9];
  const float* posw = (const float*)d_in[10];
  const float* posb = (const float*)d_in[11];
  float* o = (float*)d_out;

  dim3 grid((NW / 4) * (KK / 4));   // 12500 n-blocks x 5 k-blocks = 62500
  dim3 block(256);
  gcrl_fused<<<grid, block, 0, stream>>>(obs, pred, w1, b1, w2, b2,
                                         wih, whh, bih, bhh, posw, posb, o);
}

// Round 3
// 1174.021 us; speedup vs baseline: 1.0891x; 1.0891x over previous
//
#include <hip/hip_runtime.h>

#define T_STEPS 20
#define KK      20
#define NW      50000
#define DD      64

typedef __attribute__((ext_vector_type(8))) short bfx8;
typedef __attribute__((ext_vector_type(4))) short sx4;
typedef __attribute__((ext_vector_type(4))) float fx4;
typedef __attribute__((ext_vector_type(2))) float fx2;
typedef __attribute__((ext_vector_type(2))) int   ix2;
typedef __attribute__((ext_vector_type(4))) int   ix4;

__device__ __forceinline__ short f2bf(float f){
  unsigned u = __builtin_bit_cast(unsigned, f);
  return (short)((u + 0x7FFFu + ((u >> 16) & 1u)) >> 16);
}
__device__ __forceinline__ unsigned cvtpk(float lo, float hi){
  unsigned r; asm("v_cvt_pk_bf16_f32 %0, %1, %2" : "=v"(r) : "v"(lo), "v"(hi)); return r;
}
// clamp idioms on v_med3_f32
__device__ __forceinline__ float hsig(float x){
  return __builtin_amdgcn_fmed3f(fmaf(x, 0.16666667f, 0.5f), 0.f, 1.f);
}
__device__ __forceinline__ float htanh(float x){
  return __builtin_amdgcn_fmed3f(x, -1.f, 1.f);
}

// One consistent (group,elem)->k convention for EVERY A and B fragment (sigma).
// A/B lane-maps are identical on gfx950 (validated by R1 passing), so sigma cancels.
__device__ __forceinline__ bfx8 frag_f32(const float* p0, const float* p1){
  fx4 lo = *(const fx4*)p0, hi = *(const fx4*)p1;
  bfx8 r;
  r[0]=f2bf(lo[0]); r[1]=f2bf(lo[1]); r[2]=f2bf(lo[2]); r[3]=f2bf(lo[3]);
  r[4]=f2bf(hi[0]); r[5]=f2bf(hi[1]); r[6]=f2bf(hi[2]); r[7]=f2bf(hi[3]);
  return r;
}
__device__ __forceinline__ bfx8 frag_lds(const unsigned short* p0, const unsigned short* p1){
  sx4 lo = *(const sx4*)p0, hi = *(const sx4*)p1;
  bfx8 r;
  r[0]=lo[0]; r[1]=lo[1]; r[2]=lo[2]; r[3]=lo[3];
  r[4]=hi[0]; r[5]=hi[1]; r[6]=hi[2]; r[7]=hi[3];
  return r;
}
__device__ __forceinline__ bfx8 cat(ix2 lo, ix2 hi){
  ix4 t; t[0]=lo[0]; t[1]=lo[1]; t[2]=hi[0]; t[3]=hi[1];
  return __builtin_bit_cast(bfx8, t);
}

#define MFMA(A,B,C) __builtin_amdgcn_mfma_f32_16x16x32_bf16((A),(B),(C),0,0,0)

// Block = 32 cells, two 16-cell tiles. Tile tl, cell cc: k = k0+(cc&3), n = n0+tl*4+(cc>>2).
// Gates computed TRANSPOSED: D = W_hh (A, rows=gate j) x h^T (B, cols=cells).
// Lane (w,g,cc) output: col = cell cc, rows = j = ty*64 + w*16 + g*4 + r
//   -> after elementwise, lane holds h_new[cc][w*16+g*4 .. +3]: one aligned ds_write_b64.
// h LDS layout: [buf][tile][cell*72 + d] (stride 72 shorts = 144B -> 2-way banks, free).
__global__ __launch_bounds__(256)
void gcrl_fused(const float* __restrict__ obs, const float* __restrict__ pred,
                const float* __restrict__ w1, const float* __restrict__ b1,
                const float* __restrict__ w2, const float* __restrict__ b2,
                const float* __restrict__ wih, const float* __restrict__ whh,
                const float* __restrict__ bih, const float* __restrict__ bhh,
                const float* __restrict__ posw, const float* __restrict__ posb,
                float* __restrict__ out)
{
  __shared__ unsigned short hst[2][2][1152];   // [buf][tile][16 cells x stride 72]
  __shared__ unsigned short l1buf[2][16][36];  // [tile][cell][mid 32 + pad]
  __shared__ float xs[19][8][2];               // obs rows 0..18 for the block's 8 n's

  const int tid = threadIdx.x;
  const int w   = tid >> 6;
  const int l   = tid & 63;
  const int g   = l >> 4;
  const int cc  = l & 15;

  const int bid = blockIdx.x;
  const int k0  = (bid % 5) * 4;
  const int n0  = (bid / 5) * 8;

  // ---- stage obs into LDS ----
  for (int i = tid; i < 19 * 16; i += 256){
    int row = i >> 4, rr = i & 15;
    xs[row][rr >> 1][rr & 1] =
      obs[(size_t)row * (NW * 2) + (size_t)(n0 + (rr >> 1)) * 2 + (rr & 1)];
  }

  // ---- loop-invariant register state ----
  bfx8 wf[4][2];     // W_hh A-fragments: lane row j = ty*64 + w*16 + cc
  bfx8 a2f[4];       // x-path A-fragments (k-chunk 2): [wx0,wx1] in group-0 elems
  fx4  bs[4];        // bias C-init: rows j = ty*64 + w*16 + g*4 + r (f32!)
  #pragma unroll
  for (int ty = 0; ty < 4; ++ty){
    const int jrow = ty * 64 + w * 16 + cc;
    #pragma unroll
    for (int kt = 0; kt < 2; ++kt)
      wf[ty][kt] = frag_f32(&whh[jrow * DD + kt * 32 + g * 4],
                            &whh[jrow * DD + kt * 32 + 16 + g * 4]);
    unsigned xw = cvtpk(wih[jrow * 2 + 0], wih[jrow * 2 + 1]);
    ix4 t4; t4[0] = (g == 0) ? (int)xw : 0; t4[1] = 0; t4[2] = 0; t4[3] = 0;
    a2f[ty] = __builtin_bit_cast(bfx8, t4);
    const int jreg = ty * 64 + w * 16 + g * 4;
    bs[ty][0] = bih[jreg + 0] + bhh[jreg + 0];
    bs[ty][1] = bih[jreg + 1] + bhh[jreg + 1];
    bs[ty][2] = bih[jreg + 2] + bhh[jreg + 2];
    bs[ty][3] = bih[jreg + 3] + bhh[jreg + 3];
  }
  // projection: A = pos_w rows (rows 0,1 valid), bias via C-init (row-indexed)
  const int c2 = (cc < 2) ? cc : 0;
  bfx8 pf[2];
  #pragma unroll
  for (int kt = 0; kt < 2; ++kt)
    pf[kt] = frag_f32(&posw[c2 * DD + kt * 32 + g * 4],
                      &posw[c2 * DD + kt * 32 + 16 + g * 4]);
  fx4 pC; pC[0] = posb[0]; pC[1] = posb[1]; pC[2] = 0.f; pC[3] = 0.f;

  float* const outBase =
    out + ((size_t)(k0 + (cc & 3)) * NW + n0 + w * 4 + (cc >> 2)) * 2;

  // ---- h0 MLP stage 1: wave tl<2 handles tile tl; D[cell][j1] (as in R1) ----
  if (w < 2){
    const int tl = w;
    const int kcell = k0 + (cc & 3);
    const int ncell = n0 + tl * 4 + (cc >> 2);
    const float* Pr = pred + ((size_t)kcell * NW + ncell) * DD;
    bfx8 pa0 = frag_f32(&Pr[g * 4],      &Pr[16 + g * 4]);
    bfx8 pa1 = frag_f32(&Pr[32 + g * 4], &Pr[48 + g * 4]);
    #pragma unroll
    for (int nt = 0; nt < 2; ++nt){
      const int j1 = nt * 16 + cc;
      bfx8 bf0 = frag_f32(&w1[j1 * DD + g * 4],      &w1[j1 * DD + 16 + g * 4]);
      bfx8 bf1 = frag_f32(&w1[j1 * DD + 32 + g * 4], &w1[j1 * DD + 48 + g * 4]);
      const float bb = b1[j1];
      fx4 acc = {bb, bb, bb, bb};
      acc = MFMA(pa0, bf0, acc);
      acc = MFMA(pa1, bf1, acc);
      #pragma unroll
      for (int r = 0; r < 4; ++r){
        float xv = acc[r];
        l1buf[tl][g * 4 + r][nt * 16 + cc] =
          (unsigned short)f2bf(fmaxf(xv, 0.f) + 0.01f * fminf(xv, 0.f));
      }
    }
  }
  __syncthreads();

  // ---- h0 MLP stage 2: A = W2 rows (d), B = l1 cells -> D[d][cell]; write [cell][d] ----
  #pragma unroll
  for (int tl = 0; tl < 2; ++tl){
    bfx8 bfr = frag_lds(&l1buf[tl][cc][g * 4], &l1buf[tl][cc][16 + g * 4]);
    bfx8 afr = frag_f32(&w2[(w * 16 + cc) * 32 + g * 4],
                        &w2[(w * 16 + cc) * 32 + 16 + g * 4]);
    const int d0 = w * 16 + g * 4;
    fx4 ci; ci[0] = b2[d0]; ci[1] = b2[d0 + 1]; ci[2] = b2[d0 + 2]; ci[3] = b2[d0 + 3];
    fx4 acc = MFMA(afr, bfr, ci);
    ix2 pk;
    pk[0] = (int)cvtpk(acc[0], acc[1]);
    pk[1] = (int)cvtpk(acc[2], acc[3]);
    *(ix2*)&hst[0][tl][cc * 72 + w * 16 + g * 4] = pk;
  }
  float cA0=0.f,cA1=0.f,cA2=0.f,cA3=0.f, cB0=0.f,cB1=0.f,cB2=0.f,cB3=0.f;
  __syncthreads();

  const unsigned short* const rb = &hst[0][0][cc * 72 + g * 4];          // read base (buf0,tile0)
  unsigned short*       const wb = &hst[0][0][cc * 72 + w * 16 + g * 4]; // write base (buf0,tile0)
  // offsets in shorts: tile +1152, buf +2304

#define STEP(XI, TPREV, DOPROJ, RB, WB) do{                                    \
    const int xi_ = (XI);                                                      \
    const fx2 xA = *(const fx2*)&xs[xi_][cc >> 2][0];                          \
    const fx2 xB = *(const fx2*)&xs[xi_][4 + (cc >> 2)][0];                    \
    ix2 lA0 = *(const ix2*)(RB);         ix2 hA0 = *(const ix2*)((RB) + 16);   \
    ix2 lA1 = *(const ix2*)((RB) + 32);  ix2 hA1 = *(const ix2*)((RB) + 48);   \
    ix2 lB0 = *(const ix2*)((RB) + 1152);ix2 hB0 = *(const ix2*)((RB) + 1168); \
    ix2 lB1 = *(const ix2*)((RB) + 1184);ix2 hB1 = *(const ix2*)((RB) + 1200); \
    bfx8 hbA0 = cat(lA0, hA0), hbA1 = cat(lA1, hA1);                           \
    bfx8 hbB0 = cat(lB0, hB0), hbB1 = cat(lB1, hB1);                           \
    unsigned uA = cvtpk(xA[0], xA[1]);                                         \
    unsigned uB = cvtpk(xB[0], xB[1]);                                         \
    ix4 tA4; tA4[0] = (g == 0) ? (int)uA : 0; tA4[1]=0; tA4[2]=0; tA4[3]=0;    \
    ix4 tB4; tB4[0] = (g == 0) ? (int)uB : 0; tB4[1]=0; tB4[2]=0; tB4[3]=0;    \
    bfx8 xbA = __builtin_bit_cast(bfx8, tA4);                                  \
    bfx8 xbB = __builtin_bit_cast(bfx8, tB4);                                  \
    fx4 accA[4], accB[4];                                                      \
    _Pragma("unroll")                                                          \
    for (int ty = 0; ty < 4; ++ty){                                            \
      fx4 aa = MFMA(wf[ty][0], hbA0, bs[ty]);                                  \
      aa = MFMA(wf[ty][1], hbA1, aa);                                          \
      aa = MFMA(a2f[ty], xbA, aa);                                             \
      accA[ty] = aa;                                                           \
      fx4 ab = MFMA(wf[ty][0], hbB0, bs[ty]);                                  \
      ab = MFMA(wf[ty][1], hbB1, ab);                                          \
      ab = MFMA(a2f[ty], xbB, ab);                                             \
      accB[ty] = ab;                                                           \
    }                                                                          \
    if ((DOPROJ) && w < 2){                                                    \
      bfx8 h0 = w ? hbB0 : hbA0;                                               \
      bfx8 h1 = w ? hbB1 : hbA1;                                               \
      fx4 oa = MFMA(pf[0], h0, pC);                                            \
      oa = MFMA(pf[1], h1, oa);                                                \
      if (g == 0){                                                             \
        fx2 ov; ov[0] = oa[0]; ov[1] = oa[1];                                  \
        *(fx2*)(outBase + (size_t)(TPREV) * (KK * NW * 2)) = ov;               \
      }                                                                        \
    }                                                                          \
    {                                                                          \
      float cn0 = fmaf(hsig(accA[1][0]), cA0, hsig(accA[0][0])*htanh(accA[2][0])); \
      float cn1 = fmaf(hsig(accA[1][1]), cA1, hsig(accA[0][1])*htanh(accA[2][1])); \
      float cn2 = fmaf(hsig(accA[1][2]), cA2, hsig(accA[0][2])*htanh(accA[2][2])); \
      float cn3 = fmaf(hsig(accA[1][3]), cA3, hsig(accA[0][3])*htanh(accA[2][3])); \
      cA0=cn0; cA1=cn1; cA2=cn2; cA3=cn3;                                      \
      ix2 pk;                                                                  \
      pk[0] = (int)cvtpk(hsig(accA[3][0])*htanh(cn0), hsig(accA[3][1])*htanh(cn1)); \
      pk[1] = (int)cvtpk(hsig(accA[3][2])*htanh(cn2), hsig(accA[3][3])*htanh(cn3)); \
      *(ix2*)(WB) = pk;                                                        \
    }                                                                          \
    {                                                                          \
      float cn0 = fmaf(hsig(accB[1][0]), cB0, hsig(accB[0][0])*htanh(accB[2][0])); \
      float cn1 = fmaf(hsig(accB[1][1]), cB1, hsig(accB[0][1])*htanh(accB[2][1])); \
      float cn2 = fmaf(hsig(accB[1][2]), cB2, hsig(accB[0][2])*htanh(accB[2][2])); \
      float cn3 = fmaf(hsig(accB[1][3]), cB3, hsig(accB[0][3])*htanh(accB[2][3])); \
      cB0=cn0; cB1=cn1; cB2=cn2; cB3=cn3;                                      \
      ix2 pk;                                                                  \
      pk[0] = (int)cvtpk(hsig(accB[3][0])*htanh(cn0), hsig(accB[3][1])*htanh(cn1)); \
      pk[1] = (int)cvtpk(hsig(accB[3][2])*htanh(cn2), hsig(accB[3][3])*htanh(cn3)); \
      *(ix2*)((WB) + 1152) = pk;                                               \
    }                                                                          \
    __syncthreads();                                                           \
  }while(0)

  for (int t = 0; t < T_STEPS; t += 2){
    STEP((t == 0 ? 0 : t - 1), t - 1, (t > 0), rb,        wb + 2304);  // read buf0 -> write buf1
    STEP(t,                    t,     1,       rb + 2304, wb);         // read buf1 -> write buf0
  }

  // ---- epilogue: out[19] from h_20 (buf 0) ----
  if (w < 2){
    const unsigned short* eb = rb + w * 1152;
    ix2 l0 = *(const ix2*)eb,        h0 = *(const ix2*)(eb + 16);
    ix2 l1 = *(const ix2*)(eb + 32), h1 = *(const ix2*)(eb + 48);
    bfx8 hb0 = cat(l0, h0), hb1 = cat(l1, h1);
    fx4 oa = MFMA(pf[0], hb0, pC);
    oa = MFMA(pf[1], hb1, oa);
    if (g == 0){
      fx2 ov; ov[0] = oa[0]; ov[1] = oa[1];
      *(fx2*)(outBase + (size_t)19 * (KK * NW * 2)) = ov;
    }
  }
#undef STEP
}

extern "C" void kernel_launch(void* const* d_in, const int* in_sizes, int n_in,
                              void* d_out, int out_size, void* d_ws, size_t ws_size,
                              hipStream_t stream){
  const float* obs  = (const float*)d_in[0];
  const float* pred = (const float*)d_in[1];
  const float* w1   = (const float*)d_in[2];
  const float* b1   = (const float*)d_in[3];
  const float* w2   = (const float*)d_in[4];
  const float* b2   = (const float*)d_in[5];
  const float* wih  = (const float*)d_in[6];
  const float* whh  = (const float*)d_in[7];
  const float* bih  = (const float*)d_in[8];
  const float* bhh  = (const float*)d_in[9];
  const float* posw = (const float*)d_in[10];
  const float* posb = (const float*)d_in[11];
  float* o = (float*)d_out;

  dim3 grid(5 * (NW / 8));   // 31250 blocks x 32 cells
  dim3 block(256);
  gcrl_fused<<<grid, block, 0, stream>>>(obs, pred, w1, b1, w2, b2,
                                         wih, whh, bih, bhh, posw, posb, o);
}